// Round 9
// baseline (35.603 us; speedup 1.0000x reference)
//
#include <hip/hip_runtime.h>
#include <hip/hip_bf16.h>

// Problem constants (B,T,H,W,D = 32,16,32,32,64)
#define B_   32
#define T_   16
#define H_   32
#define W_   32
#define D_   64
#define N_   16384          // T*H*W
#define BLK  256
#define BLK_S 1024          // select block size (16 waves)
#define SEG_  8             // phase-A blocks per row
#define KPT_A 2             // keys per thread in phase A (N_/SEG_/BLK_S)
#define KPT_S 16            // keys per thread in phase B (N_/BLK_S)
#define LOSS_BLOCKS 2048
#define LOSS_ITERS  16      // (B_*N_*D_/4) / (LOSS_BLOCKS*BLK)
#define CAP 2048            // candidate list cap (level-2 expected ~2-30)
#define NBIN 2048

// LESSONS (counter-verified):
// R7: __threadfence in loss (per-block L2 writeback) -> 379 GB/s, +60us.
// R9: compacted-gather loss -> +7us vs conditional in-order streaming.
// R10: same-address device atomics finalize (MALL serialization) -> +42us.
// R11: u16 hist + bitmask vis = noise (34.5->34.3) => select-side bytes
//      don't matter; loss (~20us, ~3.3 TB/s) is the dominant term.
// => loss stays: conditional stream + per-block partial + separate finalize.

// ---------------------------------------------------------------------------
// K1a: wide phase — 256 blocks (8 per row). Computes 2048 keys each, writes
// them to the output region (overwritten by the mask in K1b), builds a
// private LDS histogram (top 11 key bits), dumps it u16-PACKED (counts
// <=2048 fit u16; halves hist traffic both sides).
// ---------------------------------------------------------------------------
__global__ __launch_bounds__(BLK_S, 1) void select_a_kernel(
    const float* __restrict__ u_g,
    const float* __restrict__ logp_t,
    const float* __restrict__ logp_h,
    const float* __restrict__ logp_w,
    unsigned* __restrict__ keys_out,    // (out+1) region, [B_][N_]
    unsigned* __restrict__ hist_out)    // ws, [B_*SEG_][NBIN/2] u32 (u16 pairs)
{
    const int ba  = blockIdx.x;          // 0..255
    const int b   = ba >> 3;
    const int sg  = ba & 7;
    const int tid = threadIdx.x;

    __shared__ float s_lt[T_], s_lh[H_], s_lw[W_];
    __shared__ unsigned s_hist[NBIN];

    if (tid < T_) s_lt[tid] = logp_t[b*T_ + tid];
    if (tid < H_) s_lh[tid] = logp_h[b*H_ + tid];
    if (tid < W_) s_lw[tid] = logp_w[b*W_ + tid];
    s_hist[tid]        = 0u;
    s_hist[tid + 1024] = 0u;
    __syncthreads();

    // NUMERICS LOCKED: stepwise fp32 -logf(-logf(u)), add order (lt+lh)+lw
    // matched the np reference exactly (absmax 0.0). Do not alter.
#pragma unroll
    for (int i = 0; i < KPT_A; ++i) {
        int   n = sg*(N_/SEG_) + i*BLK_S + tid;
        float u = u_g[b*N_ + n];
        float g = -logf(-logf(u));
        int t = n >> 10;            // / (H_*W_)
        int h = (n >> 5) & 31;
        int w = n & 31;
        float wsv = g + ((s_lt[t] + s_lh[h]) + s_lw[w]);
        unsigned bits = __float_as_uint(wsv);
        unsigned key  = (bits & 0x80000000u) ? ~bits : (bits | 0x80000000u);
        keys_out[b*N_ + n] = key;
        atomicAdd(&s_hist[key >> 21], 1u);
    }
    __syncthreads();

    // u16-packed dump: word tid holds bins {2tid, 2tid+1}
    hist_out[ba*(NBIN/2) + tid] = (s_hist[2*tid] & 0xFFFFu)
                                | (s_hist[2*tid + 1] << 16);
}

// ---------------------------------------------------------------------------
// K1b: narrow phase — 32 blocks (1 per row). Sums the 8 u16-packed
// sub-histograms IN REGISTERS, suffix-scans to find the k-th bucket,
// level-2 refine + exact threshold + tie logic (proven R6 code), writes the
// float visible mask over the key buffer AND a per-row visibility bitmask
// (ballot, 64KB total) for the loss kernel.
// ---------------------------------------------------------------------------
__global__ __launch_bounds__(BLK_S, 1) void select_b_kernel(
    unsigned* keybuf,                   // (out+1): keys in, mask (float bits) out
    const unsigned* __restrict__ hist_in, // u16-packed sub-hists
    const float* __restrict__ u_k,
    double* __restrict__ invrc,         // ws[0..31] = 1/rc_b
    unsigned long long* __restrict__ maskw) // ws: [B_][256] visibility bits
{
    const int b    = blockIdx.x;
    const int tid  = threadIdx.x;
    const int lane = tid & 63;
    const int wv   = tid >> 6;       // 0..15

    __shared__ unsigned s_hist2[NBIN];
    __shared__ unsigned s_wsum[16];
    __shared__ int s_bucket, s_above, s_cnt;
    __shared__ unsigned s_thr;
    __shared__ int s_cgt, s_ceq;
    __shared__ unsigned long long s_list[CAP];  // (key<<32)|index

    s_hist2[tid]        = 0u;
    s_hist2[tid + 1024] = 0u;
    if (tid == 0) s_cnt = 0;

    // ---- sum the 8 u16-packed sub-histograms for bins {2t,2t+1} ----
    unsigned h0 = 0, h1 = 0;
    {
        const unsigned* hb = hist_in + (size_t)b*SEG_*(NBIN/2);
#pragma unroll
        for (int j = 0; j < SEG_; ++j) {
            unsigned pw = hb[j*(NBIN/2) + tid];
            h0 += pw & 0xFFFFu;
            h1 += pw >> 16;
        }
    }

    // ---- reload this row's keys (written by phase A; cache-resident) ----
    unsigned keys[KPT_S];
#pragma unroll
    for (int i = 0; i < KPT_S; ++i)
        keys[i] = keybuf[b*N_ + i*BLK_S + tid];

    // ---- k for this row (np.linspace + fp32 mod/trunc semantics) ----
    float u0    = u_k[0];
    float strat = (b == B_-1) ? 1.0f : (float)((double)b * (1.0/31.0));
    float rate  = fmodf(u0 + strat, 1.0f);
    int   k     = (int)(16384.0f * rate);
    k = k < 1 ? 1 : (k > N_-1 ? N_-1 : k);

    // ================= level-1 suffix scan: find 11-bit bucket =============
    {
        const unsigned p = h0 + h1;
        unsigned x = p;                     // inclusive suffix sum in wave
#pragma unroll
        for (int off = 1; off < 64; off <<= 1) {
            unsigned y = __shfl_down(x, off);
            if (lane + off < 64) x += y;
        }
        if (lane == 0) s_wsum[wv] = x;
        __syncthreads();                                       // B1
        unsigned wsuf = 0;
#pragma unroll
        for (int w2 = 0; w2 < 16; ++w2) wsuf += (w2 > wv) ? s_wsum[w2] : 0u;
        const unsigned sufExcl = (x - p) + wsuf;   // keys in bins > 2t+1
        const unsigned ku = (unsigned)k;
        const unsigned a1 = sufExcl;               // above bin 2t+1
        const unsigned a0 = sufExcl + h1;          // above bin 2t
        if (a1 < ku && ku <= a1 + h1) { s_bucket = 2*tid + 1; s_above = (int)a1; }
        if (a0 < ku && ku <= a0 + h0) { s_bucket = 2*tid;     s_above = (int)a0; }
        __syncthreads();                                       // B2
    }

    const int bucket = s_bucket;        // 11-bit prefix of the k-th key
    const int above  = s_above;         // # keys in higher buckets
    const int need   = k - above;       // rank of k-th key within bucket

    // ================= level-2: histogram bucket on bits 20..10 ============
#pragma unroll
    for (int i = 0; i < KPT_S; ++i) {
        if ((int)(keys[i] >> 21) == bucket)
            atomicAdd(&s_hist2[(keys[i] >> 10) & 0x7FFu], 1u);
    }
    __syncthreads();                                           // B3

    {
        const unsigned g0 = s_hist2[2*tid];
        const unsigned g1 = s_hist2[2*tid + 1];
        const unsigned p  = g0 + g1;
        unsigned x = p;
#pragma unroll
        for (int off = 1; off < 64; off <<= 1) {
            unsigned y = __shfl_down(x, off);
            if (lane + off < 64) x += y;
        }
        if (lane == 0) s_wsum[wv] = x;
        __syncthreads();                                       // B4
        unsigned wsuf = 0;
#pragma unroll
        for (int w2 = 0; w2 < 16; ++w2) wsuf += (w2 > wv) ? s_wsum[w2] : 0u;
        const unsigned sufExcl = (x - p) + wsuf;   // in-bucket keys above 2t+1
        const unsigned ku = (unsigned)need;
        const unsigned a1 = sufExcl;
        const unsigned a0 = sufExcl + g1;
        if (a1 < ku && ku <= a1 + g1) { s_bucket = 2*tid + 1; s_above = (int)a1; }
        if (a0 < ku && ku <= a0 + g0) { s_bucket = 2*tid;     s_above = (int)a0; }
        __syncthreads();                                       // B5
    }

    const int bucket2 = s_bucket;       // bits 20..10 of the k-th key
    const int above2  = s_above;        // # in-bucket keys in higher sub-bins
    const int need2   = need - above2;  // rank within 22-bit prefix group
    const unsigned pfx22 = ((unsigned)bucket << 11) | (unsigned)bucket2;

    // ---- collect 22-bit-prefix candidates (expected ~2-30) ----
#pragma unroll
    for (int i = 0; i < KPT_S; ++i) {
        if ((keys[i] >> 10) == pfx22) {
            int slot = atomicAdd(&s_cnt, 1);
            if (slot < CAP)
                s_list[slot] = ((unsigned long long)keys[i] << 32)
                             | (unsigned)(i*BLK_S + tid);
        }
    }
    __syncthreads();                                           // B6

    // ---- exact threshold = need2-th largest among candidates ----
    const int M = s_cnt < CAP ? s_cnt : CAP;
    for (int i = tid; i < M; i += BLK_S) {
        const unsigned ki = (unsigned)(s_list[i] >> 32);
        int gt = 0, eq = 0;
        for (int j = 0; j < M; ++j) {
            const unsigned kj = (unsigned)(s_list[j] >> 32);
            gt += (kj > ki) ? 1 : 0;
            eq += (kj == ki) ? 1 : 0;
        }
        if (gt < need2 && need2 <= gt + eq) {
            s_thr = ki;                 // unique value: duplicate writers agree
            s_cgt = above + above2 + gt;    // global # keys > thr
            s_ceq = eq;                     // global # keys == thr (same pfx)
        }
    }
    __syncthreads();                                           // B7

    const unsigned thr = s_thr;
    const int count_gt = s_cgt;
    const int count_eq = s_ceq;
    const int need_eq  = k - count_gt;          // in [1, count_eq]
    const bool rare    = (count_eq != need_eq);

    // ---- write float visible mask over key buffer + ballot bitmask ----
#pragma unroll
    for (int i = 0; i < KPT_S; ++i) {
        int n = i*BLK_S + tid;
        float v;
        if (keys[i] > thr) {
            v = 1.0f;
        } else if (keys[i] == thr) {
            if (!rare || count_eq > CAP) {
                v = 1.0f;                        // all equals visible
            } else {
                int rk = 0;
                for (int j = 0; j < M; ++j) {
                    unsigned long long e = s_list[j];
                    rk += ((unsigned)(e >> 32) == thr &&
                           (int)(e & 0xFFFFFFFFull) < n) ? 1 : 0;
                }
                v = (rk < need_eq) ? 1.0f : 0.0f; // first need_eq by index
            }
        } else {
            v = 0.0f;
        }
        keybuf[b*N_ + n] = __float_as_uint(v);
        // visibility bitmask: bit lane of word (i*16 + wv); n = i*1024+wv*64+lane
        unsigned long long bal = __ballot(v == 1.0f);
        if (lane == 0) maskw[b*256 + i*16 + wv] = bal;
    }

    if (tid == 0) {
        float rc = (float)(N_ - k) / (float)N_;  // exact: power-of-2 division
        invrc[b] = 1.0 / (double)rc;
    }
}

// ---------------------------------------------------------------------------
// K2: loss. R12: LOAD/CONSUME SPLIT, 8-deep batches. The R8-R11 form kept
// the score load and its consume inside the same if-region, so the compiler
// emitted load->waitcnt->consume per iteration (~1 outstanding load/wave,
// ~3.3 TB/s). Splitting into a predicated-load loop (zero-init x[j]) and an
// unconditional consume loop lets 8 loads issue back-to-back per wave.
// Visible tokens contribute a += 0.0*w — bit-identical (a>=0 always; per-
// thread masked-add order unchanged -> same partials -> absmax 0.0).
// NO fences, NO global atomics (R7/R10 lessons).
// ---------------------------------------------------------------------------
__global__ __launch_bounds__(BLK, 1) void loss_kernel(
    const float4* __restrict__ s4,        // score as float4[8M]
    const unsigned* __restrict__ mb,      // visibility bitmask, u32 view
    const double* __restrict__ invrc,     // ws[0..31]
    double*       __restrict__ partial)   // ws[32 .. 32+LOSS_BLOCKS)
{
    const int tid = threadIdx.x;
    __shared__ double s_w[B_];
    if (tid < B_) s_w[tid] = invrc[tid];
    __syncthreads();

    const int gtid = blockIdx.x * BLK + tid;     // 0 .. 524287
    const int NT   = LOSS_BLOCKS * BLK;          // 524288 threads

    // prefetch the 16 visibility bits (broadcast words, all issue together)
    unsigned vm[LOSS_ITERS];
#pragma unroll
    for (int i = 0; i < LOSS_ITERS; ++i) {
        unsigned f = (unsigned)(gtid + i * NT);
        vm[i] = (mb[f >> 9] >> ((f >> 4) & 31)) & 1u;   // 1 = visible
    }

    double a = 0.0;
#pragma unroll
    for (int h = 0; h < 2; ++h) {
        float4 x[8];
        // batch-issue 8 predicated loads (no consumes between them)
#pragma unroll
        for (int j = 0; j < 8; ++j) {
            const int i = h*8 + j;
            x[j] = make_float4(0.f, 0.f, 0.f, 0.f);
            if (!vm[i]) x[j] = s4[gtid + i * NT];
        }
        // unconditional consume (visible -> +0.0, exact no-op on a>=0)
#pragma unroll
        for (int j = 0; j < 8; ++j) {
            const int i = h*8 + j;
            const int f = gtid + i * NT;
            float s = (x[j].x + x[j].y) + (x[j].z + x[j].w);
            a += (double)s * s_w[f >> 18];       // b = f / 262144
        }
    }

    for (int off = 32; off > 0; off >>= 1) a += __shfl_down(a, off);
    __shared__ double s_a[4];
    if ((tid & 63) == 0) s_a[tid >> 6] = a;
    __syncthreads();
    if (tid == 0) partial[blockIdx.x] = s_a[0] + s_a[1] + s_a[2] + s_a[3];
}

// ---------------------------------------------------------------------------
// K3: sum 2048 partials, finalize loss = acc / 2^25
// ---------------------------------------------------------------------------
__global__ __launch_bounds__(BLK, 1) void finalize_kernel(
    const double* __restrict__ partial,
    float* __restrict__ out)
{
    const int tid = threadIdx.x;
    double t = 0.0;
    for (int i = tid; i < LOSS_BLOCKS; i += BLK) t += partial[i];
    for (int off = 32; off > 0; off >>= 1) t += __shfl_down(t, off);
    __shared__ double s_a[4];
    if ((tid & 63) == 0) s_a[tid >> 6] = t;
    __syncthreads();
    if (tid == 0)
        out[0] = (float)((s_a[0] + s_a[1] + s_a[2] + s_a[3]) / 33554432.0);
}

extern "C" void kernel_launch(void* const* d_in, const int* in_sizes, int n_in,
                              void* d_out, int out_size, void* d_ws, size_t ws_size,
                              hipStream_t stream) {
    const float* u_g    = (const float*)d_in[0];
    const float* logp_t = (const float*)d_in[1];
    const float* logp_h = (const float*)d_in[2];
    const float* logp_w = (const float*)d_in[3];
    const float* u_k    = (const float*)d_in[4];
    const float* score  = (const float*)d_in[5];

    float*  out     = (float*)d_out;     // [0]=loss, [1..B*N]=visible (0/1)
    double* wsd     = (double*)d_ws;
    double*   invrc   = wsd;                          // 32 doubles
    double*   partial = wsd + B_;                     // 2048 doubles
    unsigned* histbuf = (unsigned*)(wsd + B_ + LOSS_BLOCKS); // [256][1024] u32
    unsigned long long* maskw =
        (unsigned long long*)(histbuf + 256*(NBIN/2));// [B_][256] u64
    unsigned* keybuf  = (unsigned*)(out + 1);         // keys, then mask bits

    select_a_kernel<<<B_*SEG_, BLK_S, 0, stream>>>(u_g, logp_t, logp_h, logp_w,
                                                   keybuf, histbuf);
    select_b_kernel<<<B_, BLK_S, 0, stream>>>(keybuf, histbuf, u_k, invrc,
                                              maskw);
    loss_kernel<<<LOSS_BLOCKS, BLK, 0, stream>>>((const float4*)score,
                                                 (const unsigned*)maskw,
                                                 invrc, partial);
    finalize_kernel<<<1, BLK, 0, stream>>>(partial, out);
}

// Round 10
// 33.942 us; speedup vs baseline: 1.0489x; 1.0489x over previous
//
#include <hip/hip_runtime.h>
#include <hip/hip_bf16.h>

// Problem constants (B,T,H,W,D = 32,16,32,32,64)
#define B_   32
#define T_   16
#define H_   32
#define W_   32
#define D_   64
#define N_   16384          // T*H*W
#define BLK  256
#define BLK_S 1024          // select block size (16 waves)
#define SEG_  8             // phase-A blocks per row
#define KPT_A 2             // keys per thread in phase A (N_/SEG_/BLK_S)
#define KPT_S 16            // keys per thread in phase B (N_/BLK_S)
#define LOSS_BLOCKS 2048
#define LOSS_ITERS  16      // (B_*N_*D_/4) / (LOSS_BLOCKS*BLK)
#define CAP 2048            // candidate list cap (level-2 expected ~2-30)
#define NBIN 2048

// LESSONS (counter-verified):
// R7:  __threadfence in loss (per-block L2 writeback) -> 379 GB/s, +60us.
// R9:  compacted-gather loss -> +7us vs conditional in-order streaming.
// R10: same-address device atomics finalize (MALL serialization) -> +42us.
// R11: u16 hist + bitmask vis = noise => select-side bytes don't matter.
// R12: load/consume split = +1.3us => loss is NOT issue-limited; the
//      conditional stream is at its DRAM-pattern floor (~4.2 TB/s eff).
// => loss core loop is LOCKED at the R11 form; no fences/atomics/gather.

// ---------------------------------------------------------------------------
// K1a: wide phase — 256 blocks (8 per row). Computes 2048 keys each, writes
// them to the output region (consumed by K1b; overwritten by the float mask
// in K2), builds a private LDS histogram (top 11 key bits), dumps it
// u16-PACKED.
// ---------------------------------------------------------------------------
__global__ __launch_bounds__(BLK_S, 1) void select_a_kernel(
    const float* __restrict__ u_g,
    const float* __restrict__ logp_t,
    const float* __restrict__ logp_h,
    const float* __restrict__ logp_w,
    unsigned* __restrict__ keys_out,    // (out+1) region, [B_][N_]
    unsigned* __restrict__ hist_out)    // ws, [B_*SEG_][NBIN/2] u32 (u16 pairs)
{
    const int ba  = blockIdx.x;          // 0..255
    const int b   = ba >> 3;
    const int sg  = ba & 7;
    const int tid = threadIdx.x;

    __shared__ float s_lt[T_], s_lh[H_], s_lw[W_];
    __shared__ unsigned s_hist[NBIN];

    if (tid < T_) s_lt[tid] = logp_t[b*T_ + tid];
    if (tid < H_) s_lh[tid] = logp_h[b*H_ + tid];
    if (tid < W_) s_lw[tid] = logp_w[b*W_ + tid];
    s_hist[tid]        = 0u;
    s_hist[tid + 1024] = 0u;
    __syncthreads();

    // NUMERICS LOCKED: stepwise fp32 -logf(-logf(u)), add order (lt+lh)+lw
    // matched the np reference exactly (absmax 0.0). Do not alter.
#pragma unroll
    for (int i = 0; i < KPT_A; ++i) {
        int   n = sg*(N_/SEG_) + i*BLK_S + tid;
        float u = u_g[b*N_ + n];
        float g = -logf(-logf(u));
        int t = n >> 10;            // / (H_*W_)
        int h = (n >> 5) & 31;
        int w = n & 31;
        float wsv = g + ((s_lt[t] + s_lh[h]) + s_lw[w]);
        unsigned bits = __float_as_uint(wsv);
        unsigned key  = (bits & 0x80000000u) ? ~bits : (bits | 0x80000000u);
        keys_out[b*N_ + n] = key;
        atomicAdd(&s_hist[key >> 21], 1u);
    }
    __syncthreads();

    // u16-packed dump: word tid holds bins {2tid, 2tid+1}
    hist_out[ba*(NBIN/2) + tid] = (s_hist[2*tid] & 0xFFFFu)
                                | (s_hist[2*tid + 1] << 16);
}

// ---------------------------------------------------------------------------
// K1b: narrow phase — 32 blocks (1 per row). Sums the 8 u16-packed
// sub-histograms IN REGISTERS, suffix-scans to find the k-th bucket,
// level-2 refine + exact threshold + tie logic (proven R6 code), and emits
// ONLY the ballot bitmask (R13: the float mask is materialized by the loss
// kernel on 256 CUs instead of 2MB of stores here on 32 CUs).
// ---------------------------------------------------------------------------
__global__ __launch_bounds__(BLK_S, 1) void select_b_kernel(
    const unsigned* __restrict__ keybuf,  // (out+1): keys from phase A
    const unsigned* __restrict__ hist_in, // u16-packed sub-hists
    const float* __restrict__ u_k,
    double* __restrict__ invrc,           // ws[0..31] = 1/rc_b
    unsigned long long* __restrict__ maskw) // ws: [B_][256] visibility bits
{
    const int b    = blockIdx.x;
    const int tid  = threadIdx.x;
    const int lane = tid & 63;
    const int wv   = tid >> 6;       // 0..15

    __shared__ unsigned s_hist2[NBIN];
    __shared__ unsigned s_wsum[16];
    __shared__ int s_bucket, s_above, s_cnt;
    __shared__ unsigned s_thr;
    __shared__ int s_cgt, s_ceq;
    __shared__ unsigned long long s_list[CAP];  // (key<<32)|index

    s_hist2[tid]        = 0u;
    s_hist2[tid + 1024] = 0u;
    if (tid == 0) s_cnt = 0;

    // ---- sum the 8 u16-packed sub-histograms for bins {2t,2t+1} ----
    unsigned h0 = 0, h1 = 0;
    {
        const unsigned* hb = hist_in + (size_t)b*SEG_*(NBIN/2);
#pragma unroll
        for (int j = 0; j < SEG_; ++j) {
            unsigned pw = hb[j*(NBIN/2) + tid];
            h0 += pw & 0xFFFFu;
            h1 += pw >> 16;
        }
    }

    // ---- reload this row's keys (written by phase A; cache-resident) ----
    unsigned keys[KPT_S];
#pragma unroll
    for (int i = 0; i < KPT_S; ++i)
        keys[i] = keybuf[b*N_ + i*BLK_S + tid];

    // ---- k for this row (np.linspace + fp32 mod/trunc semantics) ----
    float u0    = u_k[0];
    float strat = (b == B_-1) ? 1.0f : (float)((double)b * (1.0/31.0));
    float rate  = fmodf(u0 + strat, 1.0f);
    int   k     = (int)(16384.0f * rate);
    k = k < 1 ? 1 : (k > N_-1 ? N_-1 : k);

    // ================= level-1 suffix scan: find 11-bit bucket =============
    {
        const unsigned p = h0 + h1;
        unsigned x = p;                     // inclusive suffix sum in wave
#pragma unroll
        for (int off = 1; off < 64; off <<= 1) {
            unsigned y = __shfl_down(x, off);
            if (lane + off < 64) x += y;
        }
        if (lane == 0) s_wsum[wv] = x;
        __syncthreads();                                       // B1
        unsigned wsuf = 0;
#pragma unroll
        for (int w2 = 0; w2 < 16; ++w2) wsuf += (w2 > wv) ? s_wsum[w2] : 0u;
        const unsigned sufExcl = (x - p) + wsuf;   // keys in bins > 2t+1
        const unsigned ku = (unsigned)k;
        const unsigned a1 = sufExcl;               // above bin 2t+1
        const unsigned a0 = sufExcl + h1;          // above bin 2t
        if (a1 < ku && ku <= a1 + h1) { s_bucket = 2*tid + 1; s_above = (int)a1; }
        if (a0 < ku && ku <= a0 + h0) { s_bucket = 2*tid;     s_above = (int)a0; }
        __syncthreads();                                       // B2
    }

    const int bucket = s_bucket;        // 11-bit prefix of the k-th key
    const int above  = s_above;         // # keys in higher buckets
    const int need   = k - above;       // rank of k-th key within bucket

    // ================= level-2: histogram bucket on bits 20..10 ============
#pragma unroll
    for (int i = 0; i < KPT_S; ++i) {
        if ((int)(keys[i] >> 21) == bucket)
            atomicAdd(&s_hist2[(keys[i] >> 10) & 0x7FFu], 1u);
    }
    __syncthreads();                                           // B3

    {
        const unsigned g0 = s_hist2[2*tid];
        const unsigned g1 = s_hist2[2*tid + 1];
        const unsigned p  = g0 + g1;
        unsigned x = p;
#pragma unroll
        for (int off = 1; off < 64; off <<= 1) {
            unsigned y = __shfl_down(x, off);
            if (lane + off < 64) x += y;
        }
        if (lane == 0) s_wsum[wv] = x;
        __syncthreads();                                       // B4
        unsigned wsuf = 0;
#pragma unroll
        for (int w2 = 0; w2 < 16; ++w2) wsuf += (w2 > wv) ? s_wsum[w2] : 0u;
        const unsigned sufExcl = (x - p) + wsuf;   // in-bucket keys above 2t+1
        const unsigned ku = (unsigned)need;
        const unsigned a1 = sufExcl;
        const unsigned a0 = sufExcl + g1;
        if (a1 < ku && ku <= a1 + g1) { s_bucket = 2*tid + 1; s_above = (int)a1; }
        if (a0 < ku && ku <= a0 + g0) { s_bucket = 2*tid;     s_above = (int)a0; }
        __syncthreads();                                       // B5
    }

    const int bucket2 = s_bucket;       // bits 20..10 of the k-th key
    const int above2  = s_above;        // # in-bucket keys in higher sub-bins
    const int need2   = need - above2;  // rank within 22-bit prefix group
    const unsigned pfx22 = ((unsigned)bucket << 11) | (unsigned)bucket2;

    // ---- collect 22-bit-prefix candidates (expected ~2-30) ----
#pragma unroll
    for (int i = 0; i < KPT_S; ++i) {
        if ((keys[i] >> 10) == pfx22) {
            int slot = atomicAdd(&s_cnt, 1);
            if (slot < CAP)
                s_list[slot] = ((unsigned long long)keys[i] << 32)
                             | (unsigned)(i*BLK_S + tid);
        }
    }
    __syncthreads();                                           // B6

    // ---- exact threshold = need2-th largest among candidates ----
    const int M = s_cnt < CAP ? s_cnt : CAP;
    for (int i = tid; i < M; i += BLK_S) {
        const unsigned ki = (unsigned)(s_list[i] >> 32);
        int gt = 0, eq = 0;
        for (int j = 0; j < M; ++j) {
            const unsigned kj = (unsigned)(s_list[j] >> 32);
            gt += (kj > ki) ? 1 : 0;
            eq += (kj == ki) ? 1 : 0;
        }
        if (gt < need2 && need2 <= gt + eq) {
            s_thr = ki;                 // unique value: duplicate writers agree
            s_cgt = above + above2 + gt;    // global # keys > thr
            s_ceq = eq;                     // global # keys == thr (same pfx)
        }
    }
    __syncthreads();                                           // B7

    const unsigned thr = s_thr;
    const int count_gt = s_cgt;
    const int count_eq = s_ceq;
    const int need_eq  = k - count_gt;          // in [1, count_eq]
    const bool rare    = (count_eq != need_eq);

    // ---- emit visibility ballot bitmask (float mask written by K2) ----
#pragma unroll
    for (int i = 0; i < KPT_S; ++i) {
        int n = i*BLK_S + tid;
        float v;
        if (keys[i] > thr) {
            v = 1.0f;
        } else if (keys[i] == thr) {
            if (!rare || count_eq > CAP) {
                v = 1.0f;                        // all equals visible
            } else {
                int rk = 0;
                for (int j = 0; j < M; ++j) {
                    unsigned long long e = s_list[j];
                    rk += ((unsigned)(e >> 32) == thr &&
                           (int)(e & 0xFFFFFFFFull) < n) ? 1 : 0;
                }
                v = (rk < need_eq) ? 1.0f : 0.0f; // first need_eq by index
            }
        } else {
            v = 0.0f;
        }
        // bit lane of word (i*16 + wv); n = i*1024 + wv*64 + lane
        unsigned long long bal = __ballot(v == 1.0f);
        if (lane == 0) maskw[b*256 + i*16 + wv] = bal;
    }

    if (tid == 0) {
        float rc = (float)(N_ - k) / (float)N_;  // exact: power-of-2 division
        invrc[b] = 1.0 / (double)rc;
    }
}

// ---------------------------------------------------------------------------
// K2: loss. Core loop = R11-proven form (LOCKED; R12's split regressed).
// R13: also materializes the float visible mask — grid has exactly
// B_*N_ = 524288 threads, one token each: broadcast bitmask word read +
// one coalesced float store (~0.5us on 256 CUs, vs ~1.5us of stores on
// select_b's 32 CUs). NO fences, NO global atomics (R7/R10 lessons).
// ---------------------------------------------------------------------------
__global__ __launch_bounds__(BLK, 1) void loss_kernel(
    const float4* __restrict__ s4,        // score as float4[8M]
    const unsigned* __restrict__ mb,      // visibility bitmask, u32 view
    const double* __restrict__ invrc,     // ws[0..31]
    double*       __restrict__ partial,   // ws[32 .. 32+LOSS_BLOCKS)
    float*        __restrict__ visf)      // out+1: float visible mask
{
    const int tid = threadIdx.x;
    __shared__ double s_w[B_];
    if (tid < B_) s_w[tid] = invrc[tid];
    __syncthreads();

    const int gtid = blockIdx.x * BLK + tid;     // 0 .. 524287
    const int NT   = LOSS_BLOCKS * BLK;          // 524288 threads

    // materialize float mask: one token per thread (word broadcast per wave)
    {
        const unsigned tok = (unsigned)gtid;     // == b*N_ + n
        const unsigned mwu = mb[tok >> 5];
        visf[tok] = ((mwu >> (tok & 31)) & 1u) ? 1.0f : 0.0f;
    }

    // prefetch the 16 visibility bits (broadcast words, all issue together)
    unsigned vm[LOSS_ITERS];
#pragma unroll
    for (int i = 0; i < LOSS_ITERS; ++i) {
        unsigned f = (unsigned)(gtid + i * NT);
        vm[i] = (mb[f >> 9] >> ((f >> 4) & 31)) & 1u;   // 1 = visible
    }

    double a = 0.0;
#pragma unroll
    for (int i = 0; i < LOSS_ITERS; ++i) {
        int f = gtid + i * NT;
        if (!vm[i]) {                            // masked -> contributes
            float4 x = s4[f];
            float  s = (x.x + x.y) + (x.z + x.w);
            a += (double)s * s_w[f >> 18];       // b = f / 262144
        }
    }

    for (int off = 32; off > 0; off >>= 1) a += __shfl_down(a, off);
    __shared__ double s_a[4];
    if ((tid & 63) == 0) s_a[tid >> 6] = a;
    __syncthreads();
    if (tid == 0) partial[blockIdx.x] = s_a[0] + s_a[1] + s_a[2] + s_a[3];
}

// ---------------------------------------------------------------------------
// K3: sum 2048 partials, finalize loss = acc / 2^25
// ---------------------------------------------------------------------------
__global__ __launch_bounds__(BLK, 1) void finalize_kernel(
    const double* __restrict__ partial,
    float* __restrict__ out)
{
    const int tid = threadIdx.x;
    double t = 0.0;
    for (int i = tid; i < LOSS_BLOCKS; i += BLK) t += partial[i];
    for (int off = 32; off > 0; off >>= 1) t += __shfl_down(t, off);
    __shared__ double s_a[4];
    if ((tid & 63) == 0) s_a[tid >> 6] = t;
    __syncthreads();
    if (tid == 0)
        out[0] = (float)((s_a[0] + s_a[1] + s_a[2] + s_a[3]) / 33554432.0);
}

extern "C" void kernel_launch(void* const* d_in, const int* in_sizes, int n_in,
                              void* d_out, int out_size, void* d_ws, size_t ws_size,
                              hipStream_t stream) {
    const float* u_g    = (const float*)d_in[0];
    const float* logp_t = (const float*)d_in[1];
    const float* logp_h = (const float*)d_in[2];
    const float* logp_w = (const float*)d_in[3];
    const float* u_k    = (const float*)d_in[4];
    const float* score  = (const float*)d_in[5];

    float*  out     = (float*)d_out;     // [0]=loss, [1..B*N]=visible (0/1)
    double* wsd     = (double*)d_ws;
    double*   invrc   = wsd;                          // 32 doubles
    double*   partial = wsd + B_;                     // 2048 doubles
    unsigned* histbuf = (unsigned*)(wsd + B_ + LOSS_BLOCKS); // [256][1024] u32
    unsigned long long* maskw =
        (unsigned long long*)(histbuf + 256*(NBIN/2));// [B_][256] u64
    unsigned* keybuf  = (unsigned*)(out + 1);         // keys (phase A/B only)

    select_a_kernel<<<B_*SEG_, BLK_S, 0, stream>>>(u_g, logp_t, logp_h, logp_w,
                                                   keybuf, histbuf);
    select_b_kernel<<<B_, BLK_S, 0, stream>>>(keybuf, histbuf, u_k, invrc,
                                              maskw);
    loss_kernel<<<LOSS_BLOCKS, BLK, 0, stream>>>((const float4*)score,
                                                 (const unsigned*)maskw,
                                                 invrc, partial, out + 1);
    finalize_kernel<<<1, BLK, 0, stream>>>(partial, out);
}